// Round 17
// baseline (679.468 us; speedup 1.0000x reference)
//
#include <hip/hip_runtime.h>

// VQ argmin: exact bit-level emulation of numpy fp32 reference:
//   A  = np.sum(flat*flat, axis=1)     (numpy pairwise-sum tree, fp32)
//   M2 = (2*flat) @ emb.T              (BLAS: sequential fp32 fma chain over d)
//   dist = (A - M2) + ee;  argmin_k (first-min ties)
// z_e_x: [B=16, D=256, H=64, W=64] fp32; embedding: [K=1024, D=256] fp32
// out: int32 [65536]
//
// R19: raise the per-wave duty cycle. R18 (8 waves/SIMD) kept VALUBusy at
// ~62% -- occupancy doesn't fix the stall because each wave exposes its
// iteration-head scalar-load wait (z s_loads hoisted to iter top, lgkmcnt
// before first FMA; SGPR file ~102 can't hold 2 iterations -> no deeper
// scalar prefetch). Duty = compute/(compute+wait) = 512/(512+~200) = 0.72,
// the wall measured in ALL structures (R3 er-side, R16/R18 z-side).
// Fix: DSTEP 4->8 on R16's geometry (NW=16, KL=4, 4 supertiles, (256,4),
// grid 1024, direct out store, no atomics). Per iter: 8 z s_loads + 32 er
// loads at head, 512 FMA (1024cy) -> duty ~0.80. er single-buffer er[8][4]
// (32 VGPR, compile-time indices); running best in regs (R16-proven best
// choice); An at fold time (R17-proven, frees 16 SGPRs).
// Exact: per-(n,k) fmaf chain d ascending (iter d asc, row r asc, er[r]
// matches row d+r); dist=(An-acc)+ee; within-lane q asc + strict < over
// ascending supertiles; end butterfly u64 min ties->lowest k; one wave
// per n -> plain store. Semantics verified absmax=0 R13-R18.
// Pre-registered: vq > 403us => revert to R16 verbatim and declare.

#define D_DIM  256
#define K_DIM  1024
#define HW     4096
#define N_TOT  65536
#define NW     16                 // n's per wave
#define KL     4                  // k's per lane
#define DSTEP  8                  // d-rows per iteration (duty lever)
#define F32MAX 3.402823466e38f

// ---- fused prep: [0,256) et transpose | [256,768) A | [768,772) ee

__global__ void prep_kernel(const float* __restrict__ z, const float* __restrict__ e,
                            float* __restrict__ eT, float* __restrict__ A,
                            float* __restrict__ ee) {
#pragma clang fp contract(off)
    const int bid = blockIdx.x;
    const int t   = threadIdx.x;

    if (bid < 256) {
        // ---- transpose + fold the exact x2: eT[d][k] = 2*emb[k][d]
        __shared__ float tl[32][33];
        const int k0 = (bid & 31) * 32;
        const int d0 = (bid >> 5) * 32;
        const int tx = t & 31;
        const int ty = t >> 5;          // 0..7
        #pragma unroll
        for (int i = 0; i < 32; i += 8)
            tl[ty + i][tx] = 2.0f * e[(size_t)(k0 + ty + i) * D_DIM + d0 + tx];
        __syncthreads();
        #pragma unroll
        for (int i = 0; i < 32; i += 8)
            eT[(size_t)(d0 + ty + i) * K_DIM + k0 + tx] = tl[tx][ty + i];
    } else if (bid < 768) {
        // ---- A = numpy pairwise ||z_n||^2: 2 threads/n, one 128-half each
        // (independent 8-acc chains; total = s0 + s1). Bitwise-exact.
        const int tt = (bid - 256) * 256 + t;    // 0 .. 2*N_TOT-1
        const int n  = tt >> 1;
        const int h  = tt & 1;
        const int b  = n >> 12;
        const int hw = n & (HW - 1);
        const float* base = z + (size_t)b * D_DIM * HW + hw + (size_t)(h * 128) * HW;
        float r[8];
        #pragma unroll
        for (int j = 0; j < 8; ++j) { float v = base[(size_t)j * HW]; r[j] = v * v; }
        #pragma unroll
        for (int i = 8; i < 128; i += 8) {
            #pragma unroll
            for (int j = 0; j < 8; ++j) {
                float v = base[(size_t)(i + j) * HW];
                r[j] = r[j] + v * v;
            }
        }
        float s = ((r[0] + r[1]) + (r[2] + r[3])) + ((r[4] + r[5]) + (r[6] + r[7]));
        float other = __shfl_xor(s, 1);
        if (h == 0) A[n] = s + other;
    } else {
        // ---- ee = numpy pairwise ||e_k||^2 (two 128-halves of 8 accs)
        const int k = (bid - 768) * 256 + t;
        const float* row = e + (size_t)k * D_DIM;
        float total = 0.0f;
        #pragma unroll
        for (int h = 0; h < 2; ++h) {
            const float* a = row + h * 128;
            float r[8];
            #pragma unroll
            for (int j = 0; j < 8; ++j) { float v = a[j]; r[j] = v * v; }
            #pragma unroll
            for (int i = 8; i < 128; i += 8) {
                #pragma unroll
                for (int j = 0; j < 8; ++j) { float v = a[i + j]; r[j] = r[j] + v * v; }
            }
            float s = ((r[0] + r[1]) + (r[2] + r[3])) + ((r[4] + r[5]) + (r[6] + r[7]));
            total = (h == 0) ? s : (total + s);
        }
        ee[k] = total;
    }
}

// ---- main: wave owns 16 consecutive n (one b; z row = 64B contiguous,
// wave-uniform address -> compiler s_load_dwordx16) x 256 k per supertile
// (4 per lane, stride 64). Per 8-row iter: 32 er coalesced loads + 8 z
// s_loads at the head, then 512 v_fmac (1024 cy) -> duty ~0.80.

__launch_bounds__(256, 4)
__global__ void vq_kernel(const float* __restrict__ z, const float* __restrict__ eT,
                          const float* __restrict__ A, const float* __restrict__ ee,
                          int* __restrict__ out) {
#pragma clang fp contract(off)
    const int lane = threadIdx.x & 63;
    const int wid  = __builtin_amdgcn_readfirstlane(threadIdx.x >> 6);
    const int gw   = blockIdx.x * 4 + wid;       // 0..4095, wave-uniform
    const int n0   = gw * NW;
    const int b    = n0 >> 12;                   // NW | 4096: never spans b
    const int hw0  = n0 & (HW - 1);
    const float* __restrict__ zrow = z + (size_t)b * D_DIM * HW + hw0;

    unsigned int bkey[NW], bk[NW];
    #pragma unroll
    for (int i = 0; i < NW; ++i) { bkey[i] = 0xFFFFFFFFu; bk[i] = 0u; }

    #pragma unroll 1
    for (int kt = 0; kt < K_DIM / (64 * KL); ++kt) {   // 4 supertiles
        const int kb = kt * 64 * KL;
        const float* __restrict__ ep = eT + kb + lane;   // per-lane k base

        float acc[NW][KL];
        #pragma unroll
        for (int i = 0; i < NW; ++i)
            #pragma unroll
            for (int q = 0; q < KL; ++q) acc[i][q] = 0.0f;

        #pragma unroll 1
        for (int d = 0; d < D_DIM; d += DSTEP) {
            // head: issue all er loads for rows d..d+7 (32 coalesced) --
            // single-buffered, compile-time indices -> 32 VGPRs, no spill
            // pressure from ping-pong duplication.
            float er[DSTEP][KL];
            #pragma unroll
            for (int r = 0; r < DSTEP; ++r)
                #pragma unroll
                for (int q = 0; q < KL; ++q)
                    er[r][q] = ep[(size_t)(d + r) * K_DIM + q * 64];
            // compute rows d..d+7 (r ascending -> global d ascending:
            // exact per-(n,k) fmaf chain). z consumed directly (uniform
            // address -> compiler s_load_dwordx16 per row, hoisted to head).
            #pragma unroll
            for (int r = 0; r < DSTEP; ++r) {
                const float* __restrict__ zr = zrow + (size_t)(d + r) * HW;
                #pragma unroll
                for (int i = 0; i < NW; ++i) {
                    const float zv = zr[i];
                    #pragma unroll
                    for (int q = 0; q < KL; ++q)
                        acc[i][q] = fmaf(zv, er[r][q], acc[i][q]);
                }
            }
        }

        // fold supertile into running best (regs, R16-proven): q ascending
        // = k ascending per lane; strict < keeps earliest k; supertiles
        // ascend in k. An loaded here (uniform, L1-hot; keeps SGPRs free
        // for the hot loop's z s_load scheduling).
        #pragma unroll
        for (int i = 0; i < NW; ++i) {
            const float An = A[n0 + i];
            #pragma unroll
            for (int q = 0; q < KL; ++q) {
                const int kq = kb + q * 64 + lane;
                const float dist = (An - acc[i][q]) + ee[kq];
                unsigned int d32 = __float_as_uint(dist);
                d32 ^= (unsigned int)((int)d32 >> 31) | 0x80000000u;  // total order
                if (d32 < bkey[i]) { bkey[i] = d32; bk[i] = (unsigned int)kq; }
            }
        }
    }

    // cross-lane exact first-min: u64 (key, k) butterfly min over 64 lanes;
    // equal keys resolve to the lowest k. One wave per n -> plain store.
    #pragma unroll
    for (int i = 0; i < NW; ++i) {
        unsigned long long key =
            ((unsigned long long)bkey[i] << 32) | (unsigned long long)bk[i];
        #pragma unroll
        for (int m = 1; m < 64; m <<= 1) {
            unsigned long long o = __shfl_xor(key, m, 64);
            if (o < key) key = o;
        }
        if (lane == 0) out[n0 + i] = (int)(key & 0xFFFFFFFFull);
    }
}

extern "C" void kernel_launch(void* const* d_in, const int* in_sizes, int n_in,
                              void* d_out, int out_size, void* d_ws, size_t ws_size,
                              hipStream_t stream) {
    const float* z   = (const float*)d_in[0];   // [16,256,64,64]
    const float* emb = (const float*)d_in[1];   // [1024,256]
    int* out = (int*)d_out;                     // [65536] int32

    float* wsEE = (float*)d_ws;                 // 1024
    float* wsA  = wsEE + K_DIM;                 // 65536
    float* wsET = wsA + N_TOT;                  // 262144

    prep_kernel<<<772, 256, 0, stream>>>(z, emb, wsET, wsA, wsEE);
    vq_kernel<<<N_TOT / NW / 4, 256, 0, stream>>>(z, wsET, wsA, wsEE, out);
}

// Round 18
// 456.908 us; speedup vs baseline: 1.4871x; 1.4871x over previous
//
#include <hip/hip_runtime.h>

// VQ argmin: exact bit-level emulation of numpy fp32 reference:
//   A  = np.sum(flat*flat, axis=1)     (numpy pairwise-sum tree, fp32)
//   M2 = (2*flat) @ emb.T              (BLAS: sequential fp32 fma chain over d)
//   dist = (A - M2) + ee;  argmin_k (first-min ties)
// z_e_x: [B=16, D=256, H=64, W=64] fp32; embedding: [K=1024, D=256] fp32
// out: int32 [65536]
//
// R20 = R16 verbatim (pre-registered revert after R19's spill fail).
// R16 is the measured optimum of 20 variants: 465.1us total, vq 397-403,
// VALU 70%, absmax=0. Structure: lane->k mapping, NW=16 n/wave, KL=4
// k/lane, 4 supertiles of 256 k; er 2-row VGPR ping-pong (coalesced 256B
// wave loads); z consumed directly at uniform addresses -> compiler
// s_load_dwordx16 (R14/R16-proven scalarization, no spill); running best
// in registers; end-of-kernel 64-lane u64 butterfly; one wave per n ->
// plain store. (256,4), grid 1024.
// Measured exits from this point (all worse): +occupancy R18 (62% VALU at
// 8w/SIMD), +registers R19 (645MB spill), LDS best R17 (+40us pipe),
// LDS broadcast R12 (6x pipe oversubscription), LDS GEMM R9/R10, scalar
// er R3/R11 (66-70% VALU), KT/NSPLIT variants R4/R5/R8. Duty ~0.70 is
// pinned by the ~102-SGPR file: one iteration of wave-uniform operands
// fits, two don't -> per-iter lgkmcnt wait is structural.
// Exact: per-(n,k) fmaf chain d ascending; dist=(An-acc)+ee; q ascending +
// strict < over ascending supertiles; butterfly u64 min ties->lowest k.
// absmax=0 verified in this exact form (R16).

#define D_DIM  256
#define K_DIM  1024
#define HW     4096
#define N_TOT  65536
#define NW     16                 // n's per wave
#define KL     4                  // k's per lane
#define F32MAX 3.402823466e38f

// ---- fused prep: [0,256) et transpose | [256,768) A | [768,772) ee

__global__ void prep_kernel(const float* __restrict__ z, const float* __restrict__ e,
                            float* __restrict__ eT, float* __restrict__ A,
                            float* __restrict__ ee) {
#pragma clang fp contract(off)
    const int bid = blockIdx.x;
    const int t   = threadIdx.x;

    if (bid < 256) {
        // ---- transpose + fold the exact x2: eT[d][k] = 2*emb[k][d]
        __shared__ float tl[32][33];
        const int k0 = (bid & 31) * 32;
        const int d0 = (bid >> 5) * 32;
        const int tx = t & 31;
        const int ty = t >> 5;          // 0..7
        #pragma unroll
        for (int i = 0; i < 32; i += 8)
            tl[ty + i][tx] = 2.0f * e[(size_t)(k0 + ty + i) * D_DIM + d0 + tx];
        __syncthreads();
        #pragma unroll
        for (int i = 0; i < 32; i += 8)
            eT[(size_t)(d0 + ty + i) * K_DIM + k0 + tx] = tl[tx][ty + i];
    } else if (bid < 768) {
        // ---- A = numpy pairwise ||z_n||^2: 2 threads/n, one 128-half each
        // (independent 8-acc chains; total = s0 + s1). Bitwise-exact.
        const int tt = (bid - 256) * 256 + t;    // 0 .. 2*N_TOT-1
        const int n  = tt >> 1;
        const int h  = tt & 1;
        const int b  = n >> 12;
        const int hw = n & (HW - 1);
        const float* base = z + (size_t)b * D_DIM * HW + hw + (size_t)(h * 128) * HW;
        float r[8];
        #pragma unroll
        for (int j = 0; j < 8; ++j) { float v = base[(size_t)j * HW]; r[j] = v * v; }
        #pragma unroll
        for (int i = 8; i < 128; i += 8) {
            #pragma unroll
            for (int j = 0; j < 8; ++j) {
                float v = base[(size_t)(i + j) * HW];
                r[j] = r[j] + v * v;
            }
        }
        float s = ((r[0] + r[1]) + (r[2] + r[3])) + ((r[4] + r[5]) + (r[6] + r[7]));
        float other = __shfl_xor(s, 1);
        if (h == 0) A[n] = s + other;
    } else {
        // ---- ee = numpy pairwise ||e_k||^2 (two 128-halves of 8 accs)
        const int k = (bid - 768) * 256 + t;
        const float* row = e + (size_t)k * D_DIM;
        float total = 0.0f;
        #pragma unroll
        for (int h = 0; h < 2; ++h) {
            const float* a = row + h * 128;
            float r[8];
            #pragma unroll
            for (int j = 0; j < 8; ++j) { float v = a[j]; r[j] = v * v; }
            #pragma unroll
            for (int i = 8; i < 128; i += 8) {
                #pragma unroll
                for (int j = 0; j < 8; ++j) { float v = a[i + j]; r[j] = r[j] + v * v; }
            }
            float s = ((r[0] + r[1]) + (r[2] + r[3])) + ((r[4] + r[5]) + (r[6] + r[7]));
            total = (h == 0) ? s : (total + s);
        }
        ee[k] = total;
    }
}

// ---- main: wave owns 16 consecutive n (one b; z row = 64B contiguous,
// wave-uniform address -> compiler s_load_dwordx16) x 256 k per supertile
// (4 per lane, stride 64). er: 2-row VGPR ping-pong of 4 coalesced loads
// per row. Per 4-row iter: 16 er loads + 4 z s_loads + 256 v_fmac.

__launch_bounds__(256, 4)
__global__ void vq_kernel(const float* __restrict__ z, const float* __restrict__ eT,
                          const float* __restrict__ A, const float* __restrict__ ee,
                          int* __restrict__ out) {
#pragma clang fp contract(off)
    const int lane = threadIdx.x & 63;
    const int wid  = __builtin_amdgcn_readfirstlane(threadIdx.x >> 6);
    const int gw   = blockIdx.x * 4 + wid;       // 0..1023, wave-uniform
    const int n0   = gw * NW;
    const int b    = n0 >> 12;                   // NW | 4096: never spans b
    const int hw0  = n0 & (HW - 1);
    const float* __restrict__ zrow = z + (size_t)b * D_DIM * HW + hw0;

    // A[n0..n0+15]: wave-uniform -> SGPR
    float An[NW];
    #pragma unroll
    for (int i = 0; i < NW; ++i) An[i] = A[n0 + i];

    unsigned int bkey[NW], bk[NW];
    #pragma unroll
    for (int i = 0; i < NW; ++i) { bkey[i] = 0xFFFFFFFFu; bk[i] = 0u; }

    #pragma unroll 1
    for (int kt = 0; kt < K_DIM / (64 * KL); ++kt) {   // 4 supertiles
        const int kb = kt * 64 * KL;
        const float* __restrict__ ep = eT + kb + lane;   // per-lane k base

        float acc[NW][KL];
        #pragma unroll
        for (int i = 0; i < NW; ++i)
            #pragma unroll
            for (int q = 0; q < KL; ++q) acc[i][q] = 0.0f;

        // er ping-pong buffers only (16 VGPR); z is consumed directly
        // (R14-proven scalarization; NO arrays -> no spill).
        float ea[2][KL], eb[2][KL];
        #pragma unroll
        for (int r = 0; r < 2; ++r)
            #pragma unroll
            for (int q = 0; q < KL; ++q)
                ea[r][q] = ep[(size_t)r * K_DIM + q * 64];

        #pragma unroll 1
        for (int d = 0; d < D_DIM; d += 4) {
            // phase A: prefetch er rows d+2,d+3; compute rows d,d+1
            #pragma unroll
            for (int r = 0; r < 2; ++r)
                #pragma unroll
                for (int q = 0; q < KL; ++q)
                    eb[r][q] = ep[(size_t)(d + 2 + r) * K_DIM + q * 64];
            #pragma unroll
            for (int r = 0; r < 2; ++r) {
                const float* __restrict__ zr = zrow + (size_t)(d + r) * HW;
                #pragma unroll
                for (int i = 0; i < NW; ++i) {
                    const float zv = zr[i];          // uniform -> s_load
                    #pragma unroll
                    for (int q = 0; q < KL; ++q)
                        acc[i][q] = fmaf(zv, ea[r][q], acc[i][q]);
                }
            }
            // phase B: prefetch er rows d+4,d+5 (mask-wrap: tail values
            // dead, re-primed next supertile); compute rows d+2,d+3
            #pragma unroll
            for (int r = 0; r < 2; ++r) {
                const int dn = (d + 4 + r) & (D_DIM - 1);
                #pragma unroll
                for (int q = 0; q < KL; ++q)
                    ea[r][q] = ep[(size_t)dn * K_DIM + q * 64];
            }
            #pragma unroll
            for (int r = 0; r < 2; ++r) {
                const float* __restrict__ zr = zrow + (size_t)(d + 2 + r) * HW;
                #pragma unroll
                for (int i = 0; i < NW; ++i) {
                    const float zv = zr[i];          // uniform -> s_load
                    #pragma unroll
                    for (int q = 0; q < KL; ++q)
                        acc[i][q] = fmaf(zv, eb[r][q], acc[i][q]);
                }
            }
        }

        // fold supertile into running best: q ascending -> k ascending per
        // lane; strict < keeps the earliest (lowest) k.
        #pragma unroll
        for (int q = 0; q < KL; ++q) {
            const int kq = kb + q * 64 + lane;
            const float eev = ee[kq];
            #pragma unroll
            for (int i = 0; i < NW; ++i) {
                const float dist = (An[i] - acc[i][q]) + eev;
                unsigned int d32 = __float_as_uint(dist);
                d32 ^= (unsigned int)((int)d32 >> 31) | 0x80000000u;  // total order
                if (d32 < bkey[i]) { bkey[i] = d32; bk[i] = (unsigned int)kq; }
            }
        }
    }

    // cross-lane exact first-min: u64 (key, k) butterfly min over 64 lanes;
    // equal keys resolve to the lowest k. One wave per n -> plain store.
    #pragma unroll
    for (int i = 0; i < NW; ++i) {
        unsigned long long key =
            ((unsigned long long)bkey[i] << 32) | (unsigned long long)bk[i];
        #pragma unroll
        for (int m = 1; m < 64; m <<= 1) {
            unsigned long long o = __shfl_xor(key, m, 64);
            if (o < key) key = o;
        }
        if (lane == 0) out[n0 + i] = (int)(key & 0xFFFFFFFFull);
    }
}

extern "C" void kernel_launch(void* const* d_in, const int* in_sizes, int n_in,
                              void* d_out, int out_size, void* d_ws, size_t ws_size,
                              hipStream_t stream) {
    const float* z   = (const float*)d_in[0];   // [16,256,64,64]
    const float* emb = (const float*)d_in[1];   // [1024,256]
    int* out = (int*)d_out;                     // [65536] int32

    float* wsEE = (float*)d_ws;                 // 1024
    float* wsA  = wsEE + K_DIM;                 // 65536
    float* wsET = wsA + N_TOT;                  // 262144

    prep_kernel<<<772, 256, 0, stream>>>(z, emb, wsET, wsA, wsEE);
    vq_kernel<<<N_TOT / NW / 4, 256, 0, stream>>>(z, wsET, wsA, wsEE, out);
}